// Round 9
// baseline (502.964 us; speedup 1.0000x reference)
//
#include <hip/hip_runtime.h>

typedef __attribute__((ext_vector_type(8))) short bf16x8;
typedef __attribute__((ext_vector_type(4))) float f32x4;

#define WIDTH  2048
#define NHEADS 16
#define HDIM   128

__device__ __forceinline__ unsigned short f2bf(float f) {
  union { float f; unsigned int u; } v; v.f = f;
  unsigned int u = v.u;
  unsigned int r = (u + 0x7FFFu + ((u >> 16) & 1u)) >> 16;  // RNE
  return (unsigned short)r;
}

// Prep: transpose w_in/w_a [h][i][j] -> bf16 [h][j][i]; precompute
// 8*softplus(a_param)*log2(e) (so a = exp2(-ga*sp)).
__global__ __launch_bounds__(256) void prep_kernel(
    const float* __restrict__ w_in, const float* __restrict__ w_a,
    const float* __restrict__ a_param,
    unsigned short* __restrict__ wTin, unsigned short* __restrict__ wTa,
    float* __restrict__ sp8) {
  int tid = blockIdx.x * 256 + threadIdx.x;    // 0 .. 16*128*128-1
  int h   = tid >> 14;
  int rem = tid & 16383;
  int j   = rem >> 7;
  int i   = rem & 127;
  int src = (h << 14) + (i << 7) + j;
  wTin[tid] = f2bf(w_in[src]);
  wTa[tid]  = f2bf(w_a[src]);
  if (tid < WIDTH) {
    float v  = a_param[tid];
    float sp = (v > 20.0f) ? v : log1pf(__expf(v));
    sp8[tid] = 8.0f * sp * 1.4426950408889634f;   // * log2(e)
  }
}

// Zero-LDS, zero-barrier streaming:
//  - wave = 16 rows x ALL 128 cols of one head; 4 tiles per wave.
//  - x loaded once, directly into MFMA B-fragments (row l15, 128B-coalesced).
//  - weights from L1/L2 (4 same-head waves per block share the 64 KB set).
//  - epilogue x recovered via identity-MFMA transpose (verified in R8).
//  - every wave an independent latency chain; no sync anywhere.
__global__ __launch_bounds__(256, 4) void rglru_kernel(
    const float* __restrict__ x, const float* __restrict__ state,
    const float* __restrict__ b_in, const float* __restrict__ b_a,
    const unsigned short* __restrict__ wTin, const unsigned short* __restrict__ wTa,
    const float* __restrict__ sp8, float* __restrict__ out) {
  const int t    = threadIdx.x;
  const int lane = t & 63;
  const int l15  = lane & 15;
  const int l4   = lane >> 4;
  const int w    = t >> 6;

  const int b = blockIdx.x;              // 1024 blocks
  const int h = b & 15;
  const long rowbase = (long)((b >> 4) * 4 + w) * 64;   // wave's 64-row span

  const float* xh = x + h * HDIM;
  const float* sh = state + h * HDIM;
  float*       oh = out + h * HDIM;
  const unsigned short* wbi = wTin + h * HDIM * HDIM;
  const unsigned short* wba = wTa  + h * HDIM * HDIM;
  const int cb = h * HDIM;

  // identity fragments for the in-register transpose (R8-verified)
  bf16x8 idf0, idf1;
  {
    union { bf16x8 v; unsigned short us[8]; } a0, a1;
#pragma unroll
    for (int e = 0; e < 8; ++e) {
      int k = l4 * 8 + e;
      a0.us[e] = (k == l15)      ? (unsigned short)0x3F80 : (unsigned short)0;
      a1.us[e] = (k == l15 + 16) ? (unsigned short)0x3F80 : (unsigned short)0;
    }
    idf0 = a0.v; idf1 = a1.v;
  }

  // x panel prefetch registers: row l15, window q -> cols q*32 + l4*8 .. +8
  f32x4 xf32[8];
  const float* xlane = xh + l4 * 8;
#pragma unroll
  for (int q = 0; q < 4; ++q) {
    const float* p = xlane + (rowbase + l15) * WIDTH + q * 32;
    xf32[2 * q]     = *reinterpret_cast<const f32x4*>(p);
    xf32[2 * q + 1] = *reinterpret_cast<const f32x4*>(p + 4);
  }

  for (int tile = 0; tile < 4; ++tile) {
    const long row0 = rowbase + tile * 16;

    // convert landed x -> bf16 B-fragments
    bf16x8 xfr[4];
#pragma unroll
    for (int q = 0; q < 4; ++q) {
      union { bf16x8 v; unsigned int u[4]; } uu;
      f32x4 lo = xf32[2 * q], hi = xf32[2 * q + 1];
      uu.u[0] = (unsigned)f2bf(lo[0]) | ((unsigned)f2bf(lo[1]) << 16);
      uu.u[1] = (unsigned)f2bf(lo[2]) | ((unsigned)f2bf(lo[3]) << 16);
      uu.u[2] = (unsigned)f2bf(hi[0]) | ((unsigned)f2bf(hi[1]) << 16);
      uu.u[3] = (unsigned)f2bf(hi[2]) | ((unsigned)f2bf(hi[3]) << 16);
      xfr[q] = uu.v;
    }

    // prefetch next tile's x (stays in flight under this tile's compute)
    if (tile < 3) {
#pragma unroll
      for (int q = 0; q < 4; ++q) {
        const float* p = xlane + (row0 + 16 + l15) * WIDTH + q * 32;
        xf32[2 * q]     = *reinterpret_cast<const f32x4*>(p);
        xf32[2 * q + 1] = *reinterpret_cast<const f32x4*>(p + 4);
      }
    }

    const long rrow = (row0 + l15) * WIDTH;
    const f32x4 zero = (f32x4)(0.0f);

#pragma unroll
    for (int n = 0; n < 8; ++n) {
      const int colh = n * 16 + l4 * 4;
      // loads for this column group (compiler hoists/overlaps as regs allow)
      f32x4 sv = *reinterpret_cast<const f32x4*>(sh + rrow + colh);
      f32x4 bi = *reinterpret_cast<const f32x4*>(b_in + cb + colh);
      f32x4 ba = *reinterpret_cast<const f32x4*>(b_a + cb + colh);
      f32x4 sp = *reinterpret_cast<const f32x4*>(sp8 + cb + colh);

      // in-register x transpose for these 16 cols
      f32x4 xt = __builtin_amdgcn_mfma_f32_16x16x32_bf16(
          (n & 1) ? idf1 : idf0, xfr[n >> 1], zero, 0, 0, 0);

      // two block-diagonal matvecs over K=128
      f32x4 ai = zero, aa = zero;
#pragma unroll
      for (int kk = 0; kk < 4; ++kk) {
        const unsigned short* wp = (n * 16 + l15) * HDIM + kk * 32 + l4 * 8 + wbi;
        const unsigned short* wq = (n * 16 + l15) * HDIM + kk * 32 + l4 * 8 + wba;
        bf16x8 wi = *reinterpret_cast<const bf16x8*>(wp);
        bf16x8 wv = *reinterpret_cast<const bf16x8*>(wq);
        ai = __builtin_amdgcn_mfma_f32_16x16x32_bf16(wi, xfr[kk], ai, 0, 0, 0);
        aa = __builtin_amdgcn_mfma_f32_16x16x32_bf16(wv, xfr[kk], aa, 0, 0, 0);
      }

      // epilogue for 4 consecutive cols
      f32x4 o;
#pragma unroll
      for (int r = 0; r < 4; ++r) {
        float yin = ai[r] + bi[r];
        float ya  = aa[r] + ba[r];
        float gx  = __builtin_amdgcn_rcpf(1.0f + __expf(-yin));
        float ga  = __builtin_amdgcn_rcpf(1.0f + __expf(-ya));
        float av  = exp2f(-ga * sp[r]);
        float sc  = sqrtf(fmaxf(1.0f - av * av, 0.0f));
        o[r] = av * sv[r] + gx * xt[r] * sc;
      }
      *reinterpret_cast<f32x4*>(oh + rrow + colh) = o;
    }
  }
}

extern "C" void kernel_launch(void* const* d_in, const int* in_sizes, int n_in,
                              void* d_out, int out_size, void* d_ws, size_t ws_size,
                              hipStream_t stream) {
  const float* x       = (const float*)d_in[0];
  const float* state   = (const float*)d_in[1];
  const float* w_in    = (const float*)d_in[2];
  const float* b_in    = (const float*)d_in[3];
  const float* w_a     = (const float*)d_in[4];
  const float* b_a     = (const float*)d_in[5];
  const float* a_param = (const float*)d_in[6];
  float* out = (float*)d_out;

  unsigned short* wTin = (unsigned short*)d_ws;
  unsigned short* wTa  = wTin + NHEADS * HDIM * HDIM;
  float*          sp8  = (float*)(wTa + NHEADS * HDIM * HDIM);

  // prep: 16*128*128 = 262144 elements -> 1024 blocks
  hipLaunchKernelGGL(prep_kernel, dim3(1024), dim3(256), 0, stream,
                     w_in, w_a, a_param, wTin, wTa, sp8);

  // main: 4096 waves = 1024 blocks x 4 waves; wave = 64 rows x 1 head,
  // processed as 4 independent 16-row tiles. No LDS, no barriers.
  hipLaunchKernelGGL(rglru_kernel, dim3(1024), dim3(256), 0, stream,
                     x, state, b_in, b_a, wTin, wTa, sp8, out);
}

// Round 10
// 486.566 us; speedup vs baseline: 1.0337x; 1.0337x over previous
//
#include <hip/hip_runtime.h>

typedef __attribute__((ext_vector_type(8))) short bf16x8;
typedef __attribute__((ext_vector_type(4))) float f32x4;
typedef __attribute__((ext_vector_type(4))) unsigned int u32x4;

#define WIDTH  2048
#define NHEADS 16
#define HDIM   128

__device__ __forceinline__ unsigned short f2bf(float f) {
  union { float f; unsigned int u; } v; v.f = f;
  unsigned int u = v.u;
  unsigned int r = (u + 0x7FFFu + ((u >> 16) & 1u)) >> 16;  // RNE
  return (unsigned short)r;
}

// Prep: transpose w_in/w_a [h][i][j] -> bf16 [h][j][i]; precompute
// 8*softplus(a_param)*log2(e) (so a = exp2(-ga*sp)).
__global__ __launch_bounds__(256) void prep_kernel(
    const float* __restrict__ w_in, const float* __restrict__ w_a,
    const float* __restrict__ a_param,
    unsigned short* __restrict__ wTin, unsigned short* __restrict__ wTa,
    float* __restrict__ sp8) {
  int tid = blockIdx.x * 256 + threadIdx.x;    // 0 .. 16*128*128-1
  int h   = tid >> 14;
  int rem = tid & 16383;
  int j   = rem >> 7;
  int i   = rem & 127;
  int src = (h << 14) + (i << 7) + j;
  wTin[tid] = f2bf(w_in[src]);
  wTa[tid]  = f2bf(w_a[src]);
  if (tid < WIDTH) {
    float v  = a_param[tid];
    float sp = (v > 20.0f) ? v : log1pf(__expf(v));
    sp8[tid] = 8.0f * sp * 1.4426950408889634f;   // * log2(e)
  }
}

// Design (synthesis of R5/R8/R9 lessons):
//  - weights (both matrices, one head) staged ONCE into 64 KB LDS; one
//    barrier at kernel start, then zero sync for the rest of the kernel.
//  - wave = 16 rows x ALL 128 cols -> x loaded exactly once, directly into
//    MFMA B-fragments; 4 tiles per wave with 2-deep x prefetch.
//  - epilogue x recovered via identity-MFMA transpose (R8/R9-verified).
//  - 8 independent wave chains per block, 2 blocks/CU -> 16 chains/CU.
__global__ __launch_bounds__(512, 4) void rglru_kernel(
    const float* __restrict__ x, const float* __restrict__ state,
    const float* __restrict__ b_in, const float* __restrict__ b_a,
    const unsigned short* __restrict__ wTin, const unsigned short* __restrict__ wTa,
    const float* __restrict__ sp8, float* __restrict__ out) {
  __shared__ unsigned short wlds[2 * HDIM * HDIM];  // 64 KB, XOR-swizzled

  const int t    = threadIdx.x;
  const int lane = t & 63;
  const int l15  = lane & 15;
  const int l4   = lane >> 4;
  const int w    = t >> 6;          // wave 0..7

  const int b  = blockIdx.x;        // 512 blocks
  const int h  = b & 15;
  const int sb = b >> 4;            // 0..31 row-superblock
  const long rowbase = (long)sb * 512 + w * 64;   // wave's 64-row span

  const float* xh = x + h * HDIM;
  const float* sh = state + h * HDIM;
  float*       oh = out + h * HDIM;
  const int cb = h * HDIM;

  // ---- prologue x loads for tile 0 (overlap the weight staging) ----
  f32x4 xf32[8];
  const float* xlane = xh + l4 * 8;
#pragma unroll
  for (int q = 0; q < 4; ++q) {
    const float* p = xlane + (rowbase + l15) * WIDTH + q * 32;
    xf32[2 * q]     = *reinterpret_cast<const f32x4*>(p);
    xf32[2 * q + 1] = *reinterpret_cast<const f32x4*>(p + 4);
  }

  // ---- stage weights into LDS (swizzled); the ONLY barrier ----
  {
    const unsigned short* s0 = wTin + h * HDIM * HDIM;
    const unsigned short* s1 = wTa  + h * HDIM * HDIM;
#pragma unroll
    for (int it = 0; it < 4; ++it) {
      int c   = it * 512 + t;       // 16B chunk id, 0..2047
      int j   = c >> 4;             // weight row (out col) 0..127
      int sl  = c & 15;             // 16B slot within row
      int off = (j * 256 + sl * 16) ^ ((j & 7) << 4);
      *reinterpret_cast<u32x4*>(reinterpret_cast<char*>(wlds) + off) =
          *reinterpret_cast<const u32x4*>(s0 + c * 8);
      *reinterpret_cast<u32x4*>(reinterpret_cast<char*>(wlds) + 32768 + off) =
          *reinterpret_cast<const u32x4*>(s1 + c * 8);
    }
  }
  __syncthreads();

  // ---- identity fragments for the in-register x transpose ----
  bf16x8 idf0, idf1;
  {
    union { bf16x8 v; unsigned short us[8]; } a0, a1;
#pragma unroll
    for (int e = 0; e < 8; ++e) {
      int k = l4 * 8 + e;
      a0.us[e] = (k == l15)      ? (unsigned short)0x3F80 : (unsigned short)0;
      a1.us[e] = (k == l15 + 16) ? (unsigned short)0x3F80 : (unsigned short)0;
    }
    idf0 = a0.v; idf1 = a1.v;
  }

  for (int tile = 0; tile < 4; ++tile) {
    const long row0 = rowbase + tile * 16;

    // convert landed x -> bf16 B-fragments
    bf16x8 xfr[4];
#pragma unroll
    for (int q = 0; q < 4; ++q) {
      union { bf16x8 v; unsigned int u[4]; } uu;
      f32x4 lo = xf32[2 * q], hi = xf32[2 * q + 1];
      uu.u[0] = (unsigned)f2bf(lo[0]) | ((unsigned)f2bf(lo[1]) << 16);
      uu.u[1] = (unsigned)f2bf(lo[2]) | ((unsigned)f2bf(lo[3]) << 16);
      uu.u[2] = (unsigned)f2bf(hi[0]) | ((unsigned)f2bf(hi[1]) << 16);
      uu.u[3] = (unsigned)f2bf(hi[2]) | ((unsigned)f2bf(hi[3]) << 16);
      xfr[q] = uu.v;
    }

    // prefetch next tile's x (in flight under this tile's compute)
    if (tile < 3) {
#pragma unroll
      for (int q = 0; q < 4; ++q) {
        const float* p = xlane + (row0 + 16 + l15) * WIDTH + q * 32;
        xf32[2 * q]     = *reinterpret_cast<const f32x4*>(p);
        xf32[2 * q + 1] = *reinterpret_cast<const f32x4*>(p + 4);
      }
    }

    const long rrow = (row0 + l15) * WIDTH;
    const f32x4 zero = (f32x4)(0.0f);

#pragma unroll
    for (int n = 0; n < 8; ++n) {
      const int colh = n * 16 + l4 * 4;
      f32x4 sv = *reinterpret_cast<const f32x4*>(sh + rrow + colh);
      f32x4 bi = *reinterpret_cast<const f32x4*>(b_in + cb + colh);
      f32x4 ba = *reinterpret_cast<const f32x4*>(b_a + cb + colh);
      f32x4 sp = *reinterpret_cast<const f32x4*>(sp8 + cb + colh);

      // in-register x transpose for these 16 cols
      f32x4 xt = __builtin_amdgcn_mfma_f32_16x16x32_bf16(
          (n & 1) ? idf1 : idf0, xfr[n >> 1], zero, 0, 0, 0);

      // two block-diagonal matvecs over K=128, weights from LDS
      f32x4 ai = zero, aa = zero;
#pragma unroll
      for (int kk = 0; kk < 4; ++kk) {
        const int j   = n * 16 + l15;
        const int off = (j * 256 + kk * 64 + l4 * 16) ^ ((j & 7) << 4);
        bf16x8 wi = *reinterpret_cast<const bf16x8*>(
            reinterpret_cast<const char*>(wlds) + off);
        bf16x8 wv = *reinterpret_cast<const bf16x8*>(
            reinterpret_cast<const char*>(wlds) + 32768 + off);
        ai = __builtin_amdgcn_mfma_f32_16x16x32_bf16(wi, xfr[kk], ai, 0, 0, 0);
        aa = __builtin_amdgcn_mfma_f32_16x16x32_bf16(wv, xfr[kk], aa, 0, 0, 0);
      }

      // epilogue for 4 consecutive cols
      f32x4 o;
#pragma unroll
      for (int r = 0; r < 4; ++r) {
        float yin = ai[r] + bi[r];
        float ya  = aa[r] + ba[r];
        float gx  = __builtin_amdgcn_rcpf(1.0f + __expf(-yin));
        float ga  = __builtin_amdgcn_rcpf(1.0f + __expf(-ya));
        float av  = exp2f(-ga * sp[r]);
        float sc  = sqrtf(fmaxf(1.0f - av * av, 0.0f));
        o[r] = av * sv[r] + gx * xt[r] * sc;
      }
      *reinterpret_cast<f32x4*>(oh + rrow + colh) = o;
    }
  }
}

extern "C" void kernel_launch(void* const* d_in, const int* in_sizes, int n_in,
                              void* d_out, int out_size, void* d_ws, size_t ws_size,
                              hipStream_t stream) {
  const float* x       = (const float*)d_in[0];
  const float* state   = (const float*)d_in[1];
  const float* w_in    = (const float*)d_in[2];
  const float* b_in    = (const float*)d_in[3];
  const float* w_a     = (const float*)d_in[4];
  const float* b_a     = (const float*)d_in[5];
  const float* a_param = (const float*)d_in[6];
  float* out = (float*)d_out;

  unsigned short* wTin = (unsigned short*)d_ws;
  unsigned short* wTa  = wTin + NHEADS * HDIM * HDIM;
  float*          sp8  = (float*)(wTa + NHEADS * HDIM * HDIM);

  // prep: 16*128*128 = 262144 elements -> 1024 blocks
  hipLaunchKernelGGL(prep_kernel, dim3(1024), dim3(256), 0, stream,
                     w_in, w_a, a_param, wTin, wTa, sp8);

  // main: 512 blocks x 512 threads (8 waves); block = one head x 512 rows;
  // wave = 64 rows x 128 cols as 4 pipelined 16-row tiles.
  hipLaunchKernelGGL(rglru_kernel, dim3(512), dim3(512), 0, stream,
                     x, state, b_in, b_a, wTin, wTa, sp8, out);
}

// Round 12
// 102.472 us; speedup vs baseline: 4.9083x; 4.7483x over previous
//
#include <hip/hip_runtime.h>

typedef __attribute__((ext_vector_type(8))) short bf16x8;
typedef __attribute__((ext_vector_type(4))) float f32x4;
typedef __attribute__((ext_vector_type(4))) unsigned short u16x4;

#define WIDTH  2048
#define NHEADS 16
#define HDIM   128
#define BM     64

__device__ __forceinline__ unsigned short f2bf(float f) {
  union { float f; unsigned int u; } v; v.f = f;
  unsigned int u = v.u;
  unsigned int r = (u + 0x7FFFu + ((u >> 16) & 1u)) >> 16;  // RNE
  return (unsigned short)r;
}

__device__ __forceinline__ float bf2f(unsigned short s) {
  union { unsigned int u; float f; } v;
  v.u = ((unsigned int)s) << 16;
  return v.f;
}

#define LOG2E 1.4426950408889634f

// Prep: transpose w_in/w_a [h][i][j] -> bf16 [h][j][i], PRE-SCALED by log2(e)
// so the gate pre-activations are in log2 domain (sigmoid = rcp(1+exp2(-y))).
// Also: scaled biases, and sp8 = 8*softplus(a_param)*log2(e).
__global__ __launch_bounds__(256) void prep_kernel(
    const float* __restrict__ w_in, const float* __restrict__ w_a,
    const float* __restrict__ a_param,
    const float* __restrict__ b_in, const float* __restrict__ b_a,
    unsigned short* __restrict__ wTin, unsigned short* __restrict__ wTa,
    float* __restrict__ sp8, float* __restrict__ sbi, float* __restrict__ sba) {
  int tid = blockIdx.x * 256 + threadIdx.x;    // 0 .. 16*128*128-1
  int h   = tid >> 14;
  int rem = tid & 16383;
  int j   = rem >> 7;
  int i   = rem & 127;
  int src = (h << 14) + (i << 7) + j;
  wTin[tid] = f2bf(w_in[src] * LOG2E);
  wTa[tid]  = f2bf(w_a[src] * LOG2E);
  if (tid < WIDTH) {
    float v  = a_param[tid];
    float sp = (v > 20.0f) ? v : log1pf(__expf(v));
    sp8[tid] = 8.0f * sp * LOG2E;
    sbi[tid] = b_in[tid] * LOG2E;
    sba[tid] = b_a[tid] * LOG2E;
  }
}

// R5 structure (best: 114 us) + VALU diet:
//  - running pointers + immediate offsets for epilogue/weight accesses
//  - log2-domain gates (exp2 without muls)
//  - NOTE: XOR swizzle must be applied AFTER all sub-256B offsets are summed
//    (R11 bug: (A^xsw)+n*32 carries when xsw bit5 set).
__global__ __launch_bounds__(256, 4) void rglru_kernel(
    const float* __restrict__ x, const float* __restrict__ state,
    const float* __restrict__ sbi, const float* __restrict__ sba,
    const unsigned short* __restrict__ wTin, const unsigned short* __restrict__ wTa,
    const float* __restrict__ sp8, float* __restrict__ out) {
  __shared__ unsigned short xs[BM * HDIM];  // bf16 x-tile, XOR-swizzled

  const int bid  = blockIdx.x;
  const int h    = bid & (NHEADS - 1);
  const int rb   = bid >> 4;
  const int t    = threadIdx.x;
  const int lane = t & 63;
  const int wid  = t >> 6;
  const int l15  = lane & 15;
  const int l4   = lane >> 4;

  // ---- stage x tile (BM x HDIM f32 -> bf16 LDS, swizzled) ----
  const float* xtile = x + (long)rb * BM * WIDTH + h * HDIM;
#pragma unroll
  for (int it = 0; it < 8; ++it) {
    int idx = it * 256 + t;            // float4 index within tile (0..2047)
    int r   = idx >> 5;                // row 0..63
    int c4  = idx & 31;                // float4 within row
    f32x4 v = __builtin_nontemporal_load(
        reinterpret_cast<const f32x4*>(xtile + (long)r * WIDTH) + c4);
    uint2 p;
    p.x = (unsigned int)f2bf(v.x) | ((unsigned int)f2bf(v.y) << 16);
    p.y = (unsigned int)f2bf(v.z) | ((unsigned int)f2bf(v.w) << 16);
    int off = (r * 256 + c4 * 8) ^ ((r & 7) << 4);
    *reinterpret_cast<uint2*>(reinterpret_cast<char*>(xs) + off) = p;
  }
  __syncthreads();

  // ---- MFMA: acc[m][n]; m = batch-row frag, n = col frag ----
  f32x4 acc_in[4][2], acc_a[4][2];
#pragma unroll
  for (int m = 0; m < 4; ++m)
#pragma unroll
    for (int n = 0; n < 2; ++n) {
      acc_in[m][n] = (f32x4)(0.0f);
      acc_a[m][n]  = (f32x4)(0.0f);
    }

  // weight base pointers (imm offsets kk*64 B inside the loop)
  const unsigned short* wi0 = wTin + ((h * HDIM + wid * 32 + l15) * HDIM) + l4 * 8;
  const unsigned short* wi1 = wi0 + 16 * HDIM;
  const unsigned short* wa0 = wTa + ((h * HDIM + wid * 32 + l15) * HDIM) + l4 * 8;
  const unsigned short* wa1 = wa0 + 16 * HDIM;

  const int xsw = ((l15 & 7) << 4);   // per-thread swizzle bits (4..6)

#pragma unroll
  for (int kk = 0; kk < 4; ++kk) {
    bf16x8 xfr[4];
#pragma unroll
    for (int m = 0; m < 4; ++m) {
      int boff = ((m * 16 + l15) * 256 + kk * 64 + l4 * 16) ^ xsw;
      xfr[m] = *reinterpret_cast<const bf16x8*>(
          reinterpret_cast<const char*>(xs) + boff);
    }
    bf16x8 win[2], wa[2];
    win[0] = *reinterpret_cast<const bf16x8*>(wi0 + kk * 32);
    win[1] = *reinterpret_cast<const bf16x8*>(wi1 + kk * 32);
    wa[0]  = *reinterpret_cast<const bf16x8*>(wa0 + kk * 32);
    wa[1]  = *reinterpret_cast<const bf16x8*>(wa1 + kk * 32);
#pragma unroll
    for (int m = 0; m < 4; ++m)
#pragma unroll
      for (int n = 0; n < 2; ++n) {
        acc_in[m][n] = __builtin_amdgcn_mfma_f32_16x16x32_bf16(
            win[n], xfr[m], acc_in[m][n], 0, 0, 0);
        acc_a[m][n] = __builtin_amdgcn_mfma_f32_16x16x32_bf16(
            wa[n], xfr[m], acc_a[m][n], 0, 0, 0);
      }
  }

  // ---- epilogue ----
  const int cb = h * HDIM + wid * 32 + l4 * 4;
  f32x4 bi0 = *reinterpret_cast<const f32x4*>(sbi + cb);
  f32x4 bi1 = *reinterpret_cast<const f32x4*>(sbi + cb + 16);
  f32x4 ba0 = *reinterpret_cast<const f32x4*>(sba + cb);
  f32x4 ba1 = *reinterpret_cast<const f32x4*>(sba + cb + 16);
  f32x4 sp0 = *reinterpret_cast<const f32x4*>(sp8 + cb);
  f32x4 sp1 = *reinterpret_cast<const f32x4*>(sp8 + cb + 16);

  // running row pointers (advance by 16 rows per m)
  const long base = (long)(rb * BM + l15) * WIDTH + cb;
  const float* ps = state + base;
  float*       po = out + base;
  const char* pxs = reinterpret_cast<const char*>(xs);
  // XOR applied after summing ALL low-order offsets (incl. n*32); m*4096 is
  // above the swizzle bits so it can stay outside.
  const int xe0 = (l15 * 256 + (wid * 32 + l4 * 4) * 2) ^ xsw;          // n=0
  const int xe1 = (l15 * 256 + (wid * 32 + 16 + l4 * 4) * 2) ^ xsw;    // n=1

#pragma unroll
  for (int m = 0; m < 4; ++m) {
#pragma unroll
    for (int n = 0; n < 2; ++n) {
      f32x4 sv = *reinterpret_cast<const f32x4*>(ps + n * 16);
      u16x4 xb = *reinterpret_cast<const u16x4*>(
          pxs + (n ? xe1 : xe0) + m * 4096);
      f32x4 bi = n ? bi1 : bi0;
      f32x4 ba = n ? ba1 : ba0;
      f32x4 sp = n ? sp1 : sp0;
      f32x4 o;
#pragma unroll
      for (int r = 0; r < 4; ++r) {
        float yin = acc_in[m][n][r] + bi[r];
        float ya  = acc_a[m][n][r] + ba[r];
        float gx  = __builtin_amdgcn_rcpf(1.0f + exp2f(-yin));
        float ga  = __builtin_amdgcn_rcpf(1.0f + exp2f(-ya));
        float av  = exp2f(-ga * sp[r]);
        float sc  = sqrtf(fmaxf(1.0f - av * av, 0.0f));
        o[r] = av * sv[r] + gx * bf2f(xb[r]) * sc;
      }
      *reinterpret_cast<f32x4*>(po + n * 16) = o;
    }
    ps += 16 * WIDTH;
    po += 16 * WIDTH;
  }
}

extern "C" void kernel_launch(void* const* d_in, const int* in_sizes, int n_in,
                              void* d_out, int out_size, void* d_ws, size_t ws_size,
                              hipStream_t stream) {
  const float* x       = (const float*)d_in[0];
  const float* state   = (const float*)d_in[1];
  const float* w_in    = (const float*)d_in[2];
  const float* b_in    = (const float*)d_in[3];
  const float* w_a     = (const float*)d_in[4];
  const float* b_a     = (const float*)d_in[5];
  const float* a_param = (const float*)d_in[6];
  float* out = (float*)d_out;

  unsigned short* wTin = (unsigned short*)d_ws;
  unsigned short* wTa  = wTin + NHEADS * HDIM * HDIM;
  float*          sp8  = (float*)(wTa + NHEADS * HDIM * HDIM);
  float*          sbi  = sp8 + WIDTH;
  float*          sba  = sbi + WIDTH;

  // prep: 16*128*128 = 262144 elements -> 1024 blocks
  hipLaunchKernelGGL(prep_kernel, dim3(1024), dim3(256), 0, stream,
                     w_in, w_a, a_param, b_in, b_a, wTin, wTa, sp8, sbi, sba);

  // main: (16384/64) row-blocks * 16 heads = 4096 blocks
  hipLaunchKernelGGL(rglru_kernel, dim3(4096), dim3(256), 0, stream,
                     x, state, sbi, sba, wTin, wTa, sp8, out);
}